// Round 3
// baseline (288.310 us; speedup 1.0000x reference)
//
#include <hip/hip_runtime.h>

// ---------------- constants (match reference) ----------------
// B,H,W,F,D = 8,126,126,64,32 ; grid fields are (8,128,128,32)
#define NITER 20
#define OUTER 3

constexpr double DXd  = 2.0 / 9.0;     // 2/(B+1)
constexpr double DYd  = 2.0 / 127.0;   // 2/(H+1)
constexpr double DX2d = DXd * DXd;
constexpr double DY2d = DYd * DYd;
constexpr double DENd = 2.0 * (DX2d + DY2d);

constexpr float K1     = (float)(DY2d / DENd);          // * (E+W)
constexpr float K2     = (float)(DX2d / DENd);          // * (N+S)
constexpr float CC     = (float)(DX2d * DY2d / DENd);   // c coefficient
constexpr float INV2DX = (float)(1.0 / (2.0 * DXd));
constexpr float INV2DY = (float)(1.0 / (2.0 * DYd));
constexpr float INVDT  = (float)(1.0 / 0.1);
constexpr float DTDX   = (float)(0.1 / DXd);
constexpr float DTDY   = (float)(0.1 / DYd);
constexpr float PGX    = (float)(0.1 / (2.0 * 1.0 * DXd)); // DT/(2 RHO DX)
constexpr float PGY    = (float)(0.1 / (2.0 * 1.0 * DYd));
constexpr float A1     = (float)(0.1 / DX2d);            // DT/DX2
constexpr float A2     = (float)(0.1 / DY2d);            // DT/DY2
constexpr float NUf    = 0.1f;
constexpr float FDT    = 0.1f;                           // FRC*DT

__device__ __forceinline__ float bperm(int srcByte, float v) {
    return __int_as_float(__builtin_amdgcn_ds_bpermute(srcByte, __float_as_int(v)));
}

// ---------------- kernel 1: p0 = einsum(pad(x), w) + b_lin, planar [b][d][128][128]
__global__ __launch_bounds__(256) void einsum_kernel(
    const float* __restrict__ x, const float* __restrict__ w,
    const float* __restrict__ bl, float* __restrict__ p0)
{
    int id = blockIdx.x * 256 + threadIdx.x;
    int c = id & 127, r = (id >> 7) & 127, b = id >> 14;
    float acc[32];
#pragma unroll
    for (int d = 0; d < 32; ++d) acc[d] = bl[d];
    if (r >= 1 && r <= 126 && c >= 1 && c <= 126) {
        const float* xp = x + (((size_t)(b * 126 + (r - 1))) * 126 + (c - 1)) * 64;
#pragma unroll
        for (int f = 0; f < 64; f += 4) {
            float4 xv = *(const float4*)(xp + f);
#pragma unroll
            for (int d = 0; d < 32; ++d) {
                acc[d] += xv.x * w[d * 64 + f] + xv.y * w[d * 64 + f + 1]
                        + xv.z * w[d * 64 + f + 2] + xv.w * w[d * 64 + f + 3];
            }
        }
    }
    float* op = p0 + ((size_t)b * 32) * 16384 + r * 128 + c;
#pragma unroll
    for (int d = 0; d < 32; ++d) op[(size_t)d * 16384] = acc[d];
}

// ---------------- kernel 2: the full 3-outer-iteration simulation ----------------
// one workgroup per (b,d) plane; 1024 threads = 32 tx (4 cols each) x 32 ty (4 rows each)
// => 16 waves/CU = 4 waves/SIMD.
//
// VGPR budget trick (Round-2 post-mortem): the LLVM regalloc targets the occupancy
// implied by LDS usage. At 64 KiB LDS, 2 WGs/CU "fit" (160 KiB LDS/CU) -> target
// 8 waves/EU -> 64-VGPR budget -> ~320 MB/dispatch scratch spill. But our grid is
// 256 blocks on 256 CUs: the 2nd WG/CU can never exist. Padding LDS to 96 KiB
// (S[32][6][128], slots 4-5 unused) makes only 1 WG fit -> target 4 waves/EU ->
// 128-VGPR budget, which holds all ~110 live floats with no spill. Runtime
// occupancy is unchanged (1 block/CU is structural).
//
// LDS slots per ty group, time-multiplexed:
//   build_b / velocity phases: [0]=u row0 [1]=u row3 [2]=v row0 [3]=v row3
//   Jacobi phase:              ping buf A = slots {0,1}, buf B = {2,3}
// u,v halo rows are parked in registers across the Jacobi phase so the u,v seams
// may be clobbered by the p ping-pong and republished at velocity end.
__global__ __launch_bounds__(1024)
__attribute__((amdgpu_waves_per_eu(4, 4)))
void sim_kernel(
    const float* __restrict__ u0, const float* __restrict__ v0,
    const float* __restrict__ p0ws, const float* __restrict__ x,
    const float* __restrict__ w, const float* __restrict__ bl,
    float* __restrict__ out, int use_ws)
{
    __shared__ float S[32][6][128];   // 96 KiB (only slots 0..3 used; see note above)

    const int tid = threadIdx.x;
    const int tx = tid & 31, ty = tid >> 5;
    const int c0 = tx << 2, r0 = ty << 2;
    const int lane = tid & 63;
    const int srcL = (((lane & 32) | ((lane + 31) & 31)) << 2); // lane of tx-1 (periodic)
    const int srcR = (((lane & 32) | ((lane + 1) & 31)) << 2);  // lane of tx+1
    const int bb = blockIdx.x & 7;   // batch
    const int d  = blockIdx.x >> 3;  // channel
    const int tyN = (ty > 0) ? ty - 1 : 0;     // clamped: garbage masked by BC overwrite
    const int tyS = (ty < 31) ? ty + 1 : 31;

    float pC[4][4], uC[4][4], vC[4][4], cb[4][4];

    // ---- load u, v (strided channel reads, one-time) ----
#pragma unroll
    for (int r = 0; r < 4; ++r) {
        const size_t base = ((size_t)((bb * 128 + (r0 + r)) * 128 + c0)) * 32 + d;
#pragma unroll
        for (int c = 0; c < 4; ++c) {
            uC[r][c] = u0[base + (size_t)c * 32];
            vC[r][c] = v0[base + (size_t)c * 32];
        }
    }

    // ---- initial p ----
    if (use_ws) {
        const float* pp = p0ws + ((size_t)(bb * 32 + d)) * 16384;
#pragma unroll
        for (int r = 0; r < 4; ++r) {
            float4 t = *(const float4*)(pp + (r0 + r) * 128 + c0);
            pC[r][0] = t.x; pC[r][1] = t.y; pC[r][2] = t.z; pC[r][3] = t.w;
        }
    } else {
        const float blv = bl[d];
#pragma unroll
        for (int r = 0; r < 4; ++r) {
            const int gr = r0 + r;
#pragma unroll
            for (int c = 0; c < 4; ++c) {
                const int gc = c0 + c;
                float acc = blv;
                if (gr >= 1 && gr <= 126 && gc >= 1 && gc <= 126) {
                    const float* xp = x + (((size_t)(bb * 126 + (gr - 1))) * 126 + (gc - 1)) * 64;
                    for (int f = 0; f < 64; f += 4) {
                        float4 xv = *(const float4*)(xp + f);
                        acc += xv.x * w[d * 64 + f] + xv.y * w[d * 64 + f + 1]
                             + xv.z * w[d * 64 + f + 2] + xv.w * w[d * 64 + f + 3];
                    }
                }
                pC[r][c] = acc;
            }
        }
    }

    // ---- initial u,v seam publish ----
    *(float4*)&S[ty][0][c0] = make_float4(uC[0][0], uC[0][1], uC[0][2], uC[0][3]);
    *(float4*)&S[ty][1][c0] = make_float4(uC[3][0], uC[3][1], uC[3][2], uC[3][3]);
    *(float4*)&S[ty][2][c0] = make_float4(vC[0][0], vC[0][1], vC[0][2], vC[0][3]);
    *(float4*)&S[ty][3][c0] = make_float4(vC[3][0], vC[3][1], vC[3][2], vC[3][3]);
    __syncthreads();

    for (int outer = 0; outer < OUTER; ++outer) {
        // ---- read u,v halos; keep in registers through Jacobi for velocity ----
        float4 uN4 = *(const float4*)&S[tyN][1][c0];  // u row -1
        float4 uS4 = *(const float4*)&S[tyS][0][c0];  // u row 4
        float4 vN4 = *(const float4*)&S[tyN][3][c0];
        float4 vS4 = *(const float4*)&S[tyS][2][c0];
        float uNh[4] = {uN4.x, uN4.y, uN4.z, uN4.w};
        float uSh[4] = {uS4.x, uS4.y, uS4.z, uS4.w};
        float vNh[4] = {vN4.x, vN4.y, vN4.z, vN4.w};
        float vSh[4] = {vS4.x, vS4.y, vS4.z, vS4.w};

        // ================= build_b -> cb = CC * b =================
#pragma unroll
        for (int r = 0; r < 4; ++r) {
            float uWh = bperm(srcL, uC[r][3]);
            float uEh = bperm(srcR, uC[r][0]);
            float vWh = bperm(srcL, vC[r][3]);
            float vEh = bperm(srcR, vC[r][0]);
#pragma unroll
            for (int c = 0; c < 4; ++c) {
                float uE = (c < 3) ? uC[r][c + 1] : uEh;
                float uW = (c > 0) ? uC[r][c - 1] : uWh;
                float vE = (c < 3) ? vC[r][c + 1] : vEh;
                float vW = (c > 0) ? vC[r][c - 1] : vWh;
                float uN = (r > 0) ? uC[r - 1][c] : uNh[c];
                float uS_ = (r < 3) ? uC[r + 1][c] : uSh[c];
                float vN = (r > 0) ? vC[r - 1][c] : vNh[c];
                float vS_ = (r < 3) ? vC[r + 1][c] : vSh[c];
                float dudx = (uE - uW) * INV2DX;
                float dvdy = (vS_ - vN) * INV2DY;
                float dudy = (uS_ - uN) * INV2DY;
                float dvdx = (vE - vW) * INV2DX;
                float bt = (dudx + dvdy) * INVDT - dudx * dudx
                         - 2.0f * dudy * dvdx - dvdy * dvdy;   // RHO == 1
                cb[r][c] = CC * bt;    // garbage at global rows 0/127 -> p there is BC-overwritten
            }
        }
        __syncthreads();   // everyone done reading u,v seam slots
        // publish OLD p seams into buf A (slots 0,1)
        *(float4*)&S[ty][0][c0] = make_float4(pC[0][0], pC[0][1], pC[0][2], pC[0][3]);
        *(float4*)&S[ty][1][c0] = make_float4(pC[3][0], pC[3][1], pC[3][2], pC[3][3]);
        __syncthreads();

        // ================= pressure_poisson: 20 Jacobi iterations =================
        for (int it = 0; it < NITER; ++it) {
            const int rb = (it & 1) << 1;   // read buf base: 0,2,0,2,... (p-old in {0,1})
            const int wb = rb ^ 2;          // write buf base
            float4 t4 = *(const float4*)&S[tyN][rb + 1][c0];  // p row -1
            float4 b4 = *(const float4*)&S[tyS][rb + 0][c0];  // p row 4
            float nrow[4] = {t4.x, t4.y, t4.z, t4.w};
            float shalo[4] = {b4.x, b4.y, b4.z, b4.w};
            // hoisted E/W halo bperms (all from OLD pC, none overwritten yet)
            float pWh[4], pEh[4];
#pragma unroll
            for (int r = 0; r < 4; ++r) {
                pWh[r] = bperm(srcL, pC[r][3]);
                pEh[r] = bperm(srcR, pC[r][0]);
            }
#pragma unroll
            for (int r = 0; r < 4; ++r) {
                float old0[4];   // snapshot: same-row neighbors must be OLD (Jacobi)
#pragma unroll
                for (int c = 0; c < 4; ++c) old0[c] = pC[r][c];
#pragma unroll
                for (int c = 0; c < 4; ++c) {
                    float E = (c < 3) ? old0[c + 1] : pEh[r];
                    float W = (c > 0) ? old0[c - 1] : pWh[r];
                    float N = nrow[c];
                    float Sv = (r < 3) ? pC[r + 1][c] : shalo[c];
                    pC[r][c] = (E + W) * K1 + (N + Sv) * K2 - cb[r][c];
                }
#pragma unroll
                for (int c = 0; c < 4; ++c) nrow[c] = old0[c];
            }
            // row BCs (copies of NEW values); also mask the garbage edge-row computes
            if (ty == 0) {
#pragma unroll
                for (int c = 0; c < 4; ++c) pC[0][c] = pC[1][c];
            }
            if (ty == 31) {
#pragma unroll
                for (int c = 0; c < 4; ++c) pC[3][c] = pC[2][c];
            }
            *(float4*)&S[ty][wb][c0]     = make_float4(pC[0][0], pC[0][1], pC[0][2], pC[0][3]);
            *(float4*)&S[ty][wb + 1][c0] = make_float4(pC[3][0], pC[3][1], pC[3][2], pC[3][3]);
            __syncthreads();
        }
        // it=19 wrote wb=0 -> final p seams sit in slots {0,1}

        // ================= velocity_step (not needed after the last outer) =================
        if (outer < OUTER - 1) {
            float4 pt4 = *(const float4*)&S[tyN][1][c0];   // final p row -1
            float4 pb4 = *(const float4*)&S[tyS][0][c0];   // final p row 4
            float pNh[4] = {pt4.x, pt4.y, pt4.z, pt4.w};
            float pSh[4] = {pb4.x, pb4.y, pb4.z, pb4.w};

            float uNrow[4], vNrow[4];
#pragma unroll
            for (int c = 0; c < 4; ++c) { uNrow[c] = uNh[c]; vNrow[c] = vNh[c]; }
#pragma unroll
            for (int r = 0; r < 4; ++r) {
                float uold[4], vold[4];  // same-row W neighbors must be OLD
#pragma unroll
                for (int c = 0; c < 4; ++c) { uold[c] = uC[r][c]; vold[c] = vC[r][c]; }
                float uWh = bperm(srcL, uold[3]);
                float uEh = bperm(srcR, uold[0]);
                float vWh = bperm(srcL, vold[3]);
                float vEh = bperm(srcR, vold[0]);
                float pWh = bperm(srcL, pC[r][3]);
                float pEh = bperm(srcR, pC[r][0]);
#pragma unroll
                for (int c = 0; c < 4; ++c) {
                    float uc = uold[c], vc = vold[c];
                    float uE = (c < 3) ? uold[c + 1] : uEh;
                    float uW = (c > 0) ? uold[c - 1] : uWh;
                    float vE = (c < 3) ? vold[c + 1] : vEh;
                    float vW = (c > 0) ? vold[c - 1] : vWh;
                    float uN = uNrow[c];
                    float uS_ = (r < 3) ? uC[r + 1][c] : uSh[c];
                    float vN = vNrow[c];
                    float vS_ = (r < 3) ? vC[r + 1][c] : vSh[c];
                    float pE = (c < 3) ? pC[r][c + 1] : pEh;
                    float pW = (c > 0) ? pC[r][c - 1] : pWh;
                    float pN = (r > 0) ? pC[r - 1][c] : pNh[c];
                    float pS = (r < 3) ? pC[r + 1][c] : pSh[c];

                    float unew = uc - uc * DTDX * (uc - uW) - vc * DTDY * (uc - uN)
                               - PGX * (pE - pW)
                               + NUf * (A1 * (uE - 2.0f * uc + uW) + A2 * (uS_ - 2.0f * uc + uN))
                               + FDT;
                    float vnew = vc - uc * DTDX * (vc - vW) - vc * DTDY * (vc - vN)
                               - PGY * (pS - pN)
                               + NUf * (A1 * (vE - 2.0f * vc + vW) + A2 * (vS_ - 2.0f * vc + vN));
                    uC[r][c] = unew;
                    vC[r][c] = vnew;
                }
#pragma unroll
                for (int c = 0; c < 4; ++c) { uNrow[c] = uold[c]; vNrow[c] = vold[c]; }
            }
            // u,v row BCs: global rows 0 and 127 -> 0 (also masks garbage edge computes)
            if (ty == 0) {
#pragma unroll
                for (int c = 0; c < 4; ++c) { uC[0][c] = 0.0f; vC[0][c] = 0.0f; }
            }
            if (ty == 31) {
#pragma unroll
                for (int c = 0; c < 4; ++c) { uC[3][c] = 0.0f; vC[3][c] = 0.0f; }
            }
            __syncthreads();   // all p-halo reads done before seam rewrite
            *(float4*)&S[ty][0][c0] = make_float4(uC[0][0], uC[0][1], uC[0][2], uC[0][3]);
            *(float4*)&S[ty][1][c0] = make_float4(uC[3][0], uC[3][1], uC[3][2], uC[3][3]);
            *(float4*)&S[ty][2][c0] = make_float4(vC[0][0], vC[0][1], vC[0][2], vC[0][3]);
            *(float4*)&S[ty][3][c0] = make_float4(vC[3][0], vC[3][1], vC[3][2], vC[3][3]);
            __syncthreads();
        }
    }

    // ---- output: p[:, row 127, :, :] -> out[b][col][d] ----
    if (ty == 31) {
        float* op = out + ((size_t)bb * 128 + c0) * 32 + d;
        op[0]  = pC[3][0];
        op[32] = pC[3][1];
        op[64] = pC[3][2];
        op[96] = pC[3][3];
    }
}

extern "C" void kernel_launch(void* const* d_in, const int* in_sizes, int n_in,
                              void* d_out, int out_size, void* d_ws, size_t ws_size,
                              hipStream_t stream) {
    const float* x  = (const float*)d_in[0];
    const float* u0 = (const float*)d_in[1];
    const float* v0 = (const float*)d_in[2];
    const float* w  = (const float*)d_in[3];
    const float* bl = (const float*)d_in[4];
    float* out = (float*)d_out;
    float* p0  = (float*)d_ws;

    const size_t need = (size_t)8 * 32 * 128 * 128 * sizeof(float);
    const int use_ws = (ws_size >= need) ? 1 : 0;

    if (use_ws) {
        einsum_kernel<<<512, 256, 0, stream>>>(x, w, bl, p0);
    }
    sim_kernel<<<256, 1024, 0, stream>>>(u0, v0, p0, x, w, bl, out, use_ws);
}

// Round 4
// 246.800 us; speedup vs baseline: 1.1682x; 1.1682x over previous
//
#include <hip/hip_runtime.h>

// ---------------- constants (match reference) ----------------
// B,H,W,F,D = 8,126,126,64,32 ; grid fields are (8,128,128,32)
#define NITER 20
#define OUTER 3

constexpr double DXd  = 2.0 / 9.0;     // 2/(B+1)
constexpr double DYd  = 2.0 / 127.0;   // 2/(H+1)
constexpr double DX2d = DXd * DXd;
constexpr double DY2d = DYd * DYd;
constexpr double DENd = 2.0 * (DX2d + DY2d);

constexpr float K1     = (float)(DY2d / DENd);          // * (E+W)
constexpr float K2     = (float)(DX2d / DENd);          // * (N+S)
constexpr float CC     = (float)(DX2d * DY2d / DENd);   // c coefficient
constexpr float INV2DX = (float)(1.0 / (2.0 * DXd));
constexpr float INV2DY = (float)(1.0 / (2.0 * DYd));
constexpr float INVDT  = (float)(1.0 / 0.1);
constexpr float DTDX   = (float)(0.1 / DXd);
constexpr float DTDY   = (float)(0.1 / DYd);
constexpr float PGX    = (float)(0.1 / (2.0 * 1.0 * DXd)); // DT/(2 RHO DX)
constexpr float PGY    = (float)(0.1 / (2.0 * 1.0 * DYd));
constexpr float A1     = (float)(0.1 / DX2d);            // DT/DX2
constexpr float A2     = (float)(0.1 / DY2d);            // DT/DY2
constexpr float NUf    = 0.1f;
constexpr float FDT    = 0.1f;                           // FRC*DT

__device__ __forceinline__ float bperm(int srcByte, float v) {
    return __int_as_float(__builtin_amdgcn_ds_bpermute(srcByte, __float_as_int(v)));
}

// ---------------- kernel 1: p0 = einsum(pad(x), w) + b_lin, planar [b][d][128][128]
__global__ __launch_bounds__(256) void einsum_kernel(
    const float* __restrict__ x, const float* __restrict__ w,
    const float* __restrict__ bl, float* __restrict__ p0)
{
    int id = blockIdx.x * 256 + threadIdx.x;
    int c = id & 127, r = (id >> 7) & 127, b = id >> 14;
    float acc[32];
#pragma unroll
    for (int d = 0; d < 32; ++d) acc[d] = bl[d];
    if (r >= 1 && r <= 126 && c >= 1 && c <= 126) {
        const float* xp = x + (((size_t)(b * 126 + (r - 1))) * 126 + (c - 1)) * 64;
#pragma unroll
        for (int f = 0; f < 64; f += 4) {
            float4 xv = *(const float4*)(xp + f);
#pragma unroll
            for (int d = 0; d < 32; ++d) {
                acc[d] += xv.x * w[d * 64 + f] + xv.y * w[d * 64 + f + 1]
                        + xv.z * w[d * 64 + f + 2] + xv.w * w[d * 64 + f + 3];
            }
        }
    }
    float* op = p0 + ((size_t)b * 32) * 16384 + r * 128 + c;
#pragma unroll
    for (int d = 0; d < 32; ++d) op[(size_t)d * 16384] = acc[d];
}

// ---------------- kernel 2: the full 3-outer-iteration simulation ----------------
// one workgroup per (b,d) plane; 512 threads = 32 tx (4 cols each) x 16 ty (8 rows each).
//
// Round-4 structure decision: the 1024-thread shape is unfixable (LLVM pins a
// 64-VGPR budget for 1024-thread blocks regardless of launch_bounds /
// amdgpu_waves_per_eu / LDS-occupancy shaping; verified over 3 rounds ->
// ~320 MB/dispatch scratch spill). The 512-thread shape reliably gets 128 VGPRs
// and ZERO spill (Round 0: FETCH == input footprint). Kept from R1-R3 (all
// passed correctness): no valid-masks (garbage edge rows are BC-overwritten),
// and the last velocity_step is skipped (output is p only).
__global__ __launch_bounds__(512, 2) void sim_kernel(
    const float* __restrict__ u0, const float* __restrict__ v0,
    const float* __restrict__ p0ws, const float* __restrict__ x,
    const float* __restrict__ w, const float* __restrict__ bl,
    float* __restrict__ out, int use_ws)
{
    __shared__ float sP[2][16][2][128];  // ping-pong p seam rows (r0, r0+7) per ty
    __shared__ float sU[16][2][128];
    __shared__ float sV[16][2][128];

    const int tid = threadIdx.x;
    const int tx = tid & 31, ty = tid >> 5;
    const int c0 = tx << 2, r0 = ty << 3;
    const int lane = tid & 63;
    const int srcL = (((lane & 32) | ((lane + 31) & 31)) << 2); // lane of tx-1 (periodic)
    const int srcR = (((lane & 32) | ((lane + 1) & 31)) << 2);  // lane of tx+1
    const int bb = blockIdx.x & 7;   // batch
    const int d  = blockIdx.x >> 3;  // channel

    float pC[8][4], uC[8][4], vC[8][4], cb[8][4];

    // ---- load u, v (strided channel reads) ----
#pragma unroll
    for (int r = 0; r < 8; ++r) {
        const size_t base = ((size_t)((bb * 128 + (r0 + r)) * 128 + c0)) * 32 + d;
#pragma unroll
        for (int c = 0; c < 4; ++c) {
            uC[r][c] = u0[base + (size_t)c * 32];
            vC[r][c] = v0[base + (size_t)c * 32];
        }
    }

    // ---- initial p ----
    if (use_ws) {
        const float* pp = p0ws + ((size_t)(bb * 32 + d)) * 16384;
#pragma unroll
        for (int r = 0; r < 8; ++r) {
            float4 t = *(const float4*)(pp + (r0 + r) * 128 + c0);
            pC[r][0] = t.x; pC[r][1] = t.y; pC[r][2] = t.z; pC[r][3] = t.w;
        }
    } else {
        const float blv = bl[d];
#pragma unroll
        for (int r = 0; r < 8; ++r) {
            const int gr = r0 + r;
#pragma unroll
            for (int c = 0; c < 4; ++c) {
                const int gc = c0 + c;
                float acc = blv;
                if (gr >= 1 && gr <= 126 && gc >= 1 && gc <= 126) {
                    const float* xp = x + (((size_t)(bb * 126 + (gr - 1))) * 126 + (gc - 1)) * 64;
                    for (int f = 0; f < 64; f += 4) {
                        float4 xv = *(const float4*)(xp + f);
                        acc += xv.x * w[d * 64 + f] + xv.y * w[d * 64 + f + 1]
                             + xv.z * w[d * 64 + f + 2] + xv.w * w[d * 64 + f + 3];
                    }
                }
                pC[r][c] = acc;
            }
        }
    }

    // ---- initial seams ----
    int s = 0;
    *(float4*)&sP[0][ty][0][c0] = make_float4(pC[0][0], pC[0][1], pC[0][2], pC[0][3]);
    *(float4*)&sP[0][ty][1][c0] = make_float4(pC[7][0], pC[7][1], pC[7][2], pC[7][3]);
    *(float4*)&sU[ty][0][c0]    = make_float4(uC[0][0], uC[0][1], uC[0][2], uC[0][3]);
    *(float4*)&sU[ty][1][c0]    = make_float4(uC[7][0], uC[7][1], uC[7][2], uC[7][3]);
    *(float4*)&sV[ty][0][c0]    = make_float4(vC[0][0], vC[0][1], vC[0][2], vC[0][3]);
    *(float4*)&sV[ty][1][c0]    = make_float4(vC[7][0], vC[7][1], vC[7][2], vC[7][3]);
    __syncthreads();

    const int tyN = (ty > 0) ? ty - 1 : 0;    // clamped: garbage rows masked by BC overwrite
    const int tyS = (ty < 15) ? ty + 1 : 15;

    for (int outer = 0; outer < OUTER; ++outer) {
        // ================= build_b -> cb = CC * b =================
        {
            float4 uN4 = *(const float4*)&sU[tyN][1][c0];
            float4 uS4 = *(const float4*)&sU[tyS][0][c0];
            float4 vN4 = *(const float4*)&sV[tyN][1][c0];
            float4 vS4 = *(const float4*)&sV[tyS][0][c0];
            float uNh[4] = {uN4.x, uN4.y, uN4.z, uN4.w};
            float uSh[4] = {uS4.x, uS4.y, uS4.z, uS4.w};
            float vNh[4] = {vN4.x, vN4.y, vN4.z, vN4.w};
            float vSh[4] = {vS4.x, vS4.y, vS4.z, vS4.w};
#pragma unroll
            for (int r = 0; r < 8; ++r) {
                float uWh = bperm(srcL, uC[r][3]);
                float uEh = bperm(srcR, uC[r][0]);
                float vWh = bperm(srcL, vC[r][3]);
                float vEh = bperm(srcR, vC[r][0]);
#pragma unroll
                for (int c = 0; c < 4; ++c) {
                    float uE = (c < 3) ? uC[r][c + 1] : uEh;
                    float uW = (c > 0) ? uC[r][c - 1] : uWh;
                    float vE = (c < 3) ? vC[r][c + 1] : vEh;
                    float vW = (c > 0) ? vC[r][c - 1] : vWh;
                    float uN = (r > 0) ? uC[r - 1][c] : uNh[c];
                    float uS = (r < 7) ? uC[r + 1][c] : uSh[c];
                    float vN = (r > 0) ? vC[r - 1][c] : vNh[c];
                    float vS = (r < 7) ? vC[r + 1][c] : vSh[c];
                    float dudx = (uE - uW) * INV2DX;
                    float dvdy = (vS - vN) * INV2DY;
                    float dudy = (uS - uN) * INV2DY;
                    float dvdx = (vE - vW) * INV2DX;
                    float bt = (dudx + dvdy) * INVDT - dudx * dudx
                             - 2.0f * dudy * dvdx - dvdy * dvdy;   // RHO == 1
                    cb[r][c] = CC * bt;   // garbage at rows 0/127: p there is BC-overwritten
                }
            }
        }

        // ================= pressure_poisson: 20 Jacobi iterations =================
        for (int it = 0; it < NITER; ++it) {
            float4 t4 = *(const float4*)&sP[s][tyN][1][c0];
            float4 b4 = *(const float4*)&sP[s][tyS][0][c0];
            float nrow[4] = {t4.x, t4.y, t4.z, t4.w};
            float shalo[4] = {b4.x, b4.y, b4.z, b4.w};
#pragma unroll
            for (int r = 0; r < 8; ++r) {
                float old0[4];   // snapshot: ALL same-row neighbors must be OLD (Jacobi)
#pragma unroll
                for (int c = 0; c < 4; ++c) old0[c] = pC[r][c];
                float pWh = bperm(srcL, old0[3]);
                float pEh = bperm(srcR, old0[0]);
#pragma unroll
                for (int c = 0; c < 4; ++c) {
                    float E = (c < 3) ? old0[c + 1] : pEh;
                    float W = (c > 0) ? old0[c - 1] : pWh;
                    float N = nrow[c];
                    float S = (r < 7) ? pC[r + 1][c] : shalo[c];
                    pC[r][c] = (E + W) * K1 + (N + S) * K2 - cb[r][c];
                }
#pragma unroll
                for (int c = 0; c < 4; ++c) nrow[c] = old0[c];
            }
            // row BCs (copy of NEW values); also masks the garbage edge-row computes
            if (ty == 0) {
#pragma unroll
                for (int c = 0; c < 4; ++c) pC[0][c] = pC[1][c];
            }
            if (ty == 15) {
#pragma unroll
                for (int c = 0; c < 4; ++c) pC[7][c] = pC[6][c];
            }
            // publish new seam rows into the other buffer; single barrier
            *(float4*)&sP[s ^ 1][ty][0][c0] = make_float4(pC[0][0], pC[0][1], pC[0][2], pC[0][3]);
            *(float4*)&sP[s ^ 1][ty][1][c0] = make_float4(pC[7][0], pC[7][1], pC[7][2], pC[7][3]);
            __syncthreads();
            s ^= 1;
        }

        // ================= velocity_step (skipped after last outer: output is p) ========
        if (outer < OUTER - 1) {
            float4 ut4 = *(const float4*)&sU[tyN][1][c0];
            float4 us4 = *(const float4*)&sU[tyS][0][c0];
            float4 vt4 = *(const float4*)&sV[tyN][1][c0];
            float4 vs4 = *(const float4*)&sV[tyS][0][c0];
            float4 pt4 = *(const float4*)&sP[s][tyN][1][c0];
            float4 pb4 = *(const float4*)&sP[s][tyS][0][c0];
            float uNh[4] = {ut4.x, ut4.y, ut4.z, ut4.w};
            float uSh[4] = {us4.x, us4.y, us4.z, us4.w};
            float vNh[4] = {vt4.x, vt4.y, vt4.z, vt4.w};
            float vSh[4] = {vs4.x, vs4.y, vs4.z, vs4.w};
            float pNh[4] = {pt4.x, pt4.y, pt4.z, pt4.w};
            float pSh[4] = {pb4.x, pb4.y, pb4.z, pb4.w};
            __syncthreads();   // all seam reads done before the rewrites below

            float uNrow[4], vNrow[4];
#pragma unroll
            for (int c = 0; c < 4; ++c) { uNrow[c] = uNh[c]; vNrow[c] = vNh[c]; }
#pragma unroll
            for (int r = 0; r < 8; ++r) {
                float uold[4], vold[4];  // snapshot: same-row W neighbors must be OLD
#pragma unroll
                for (int c = 0; c < 4; ++c) { uold[c] = uC[r][c]; vold[c] = vC[r][c]; }
                float uWh = bperm(srcL, uold[3]);
                float uEh = bperm(srcR, uold[0]);
                float vWh = bperm(srcL, vold[3]);
                float vEh = bperm(srcR, vold[0]);
                float pWh = bperm(srcL, pC[r][3]);
                float pEh = bperm(srcR, pC[r][0]);
#pragma unroll
                for (int c = 0; c < 4; ++c) {
                    float uc = uold[c], vc = vold[c];
                    float uE = (c < 3) ? uold[c + 1] : uEh;
                    float uW = (c > 0) ? uold[c - 1] : uWh;
                    float vE = (c < 3) ? vold[c + 1] : vEh;
                    float vW = (c > 0) ? vold[c - 1] : vWh;
                    float uN = uNrow[c];
                    float uS = (r < 7) ? uC[r + 1][c] : uSh[c];
                    float vN = vNrow[c];
                    float vS = (r < 7) ? vC[r + 1][c] : vSh[c];
                    float pE = (c < 3) ? pC[r][c + 1] : pEh;
                    float pW = (c > 0) ? pC[r][c - 1] : pWh;
                    float pN = (r > 0) ? pC[r - 1][c] : pNh[c];
                    float pS = (r < 7) ? pC[r + 1][c] : pSh[c];

                    float unew = uc - uc * DTDX * (uc - uW) - vc * DTDY * (uc - uN)
                               - PGX * (pE - pW)
                               + NUf * (A1 * (uE - 2.0f * uc + uW) + A2 * (uS - 2.0f * uc + uN))
                               + FDT;
                    float vnew = vc - uc * DTDX * (vc - vW) - vc * DTDY * (vc - vN)
                               - PGY * (pS - pN)
                               + NUf * (A1 * (vE - 2.0f * vc + vW) + A2 * (vS - 2.0f * vc + vN));
                    uC[r][c] = unew;
                    vC[r][c] = vnew;
                }
#pragma unroll
                for (int c = 0; c < 4; ++c) { uNrow[c] = uold[c]; vNrow[c] = vold[c]; }
            }
            // u,v row BCs: rows 0 and 127 -> 0 (also masks garbage edge computes)
            if (ty == 0) {
#pragma unroll
                for (int c = 0; c < 4; ++c) { uC[0][c] = 0.0f; vC[0][c] = 0.0f; }
            }
            if (ty == 15) {
#pragma unroll
                for (int c = 0; c < 4; ++c) { uC[7][c] = 0.0f; vC[7][c] = 0.0f; }
            }
            *(float4*)&sU[ty][0][c0] = make_float4(uC[0][0], uC[0][1], uC[0][2], uC[0][3]);
            *(float4*)&sU[ty][1][c0] = make_float4(uC[7][0], uC[7][1], uC[7][2], uC[7][3]);
            *(float4*)&sV[ty][0][c0] = make_float4(vC[0][0], vC[0][1], vC[0][2], vC[0][3]);
            *(float4*)&sV[ty][1][c0] = make_float4(vC[7][0], vC[7][1], vC[7][2], vC[7][3]);
            __syncthreads();
        }
    }

    // ---- output: p[:, row 127, :, :]  -> out[b][col][d] ----
    if (ty == 15) {
        float* op = out + ((size_t)bb * 128 + c0) * 32 + d;
        op[0]  = pC[7][0];
        op[32] = pC[7][1];
        op[64] = pC[7][2];
        op[96] = pC[7][3];
    }
}

extern "C" void kernel_launch(void* const* d_in, const int* in_sizes, int n_in,
                              void* d_out, int out_size, void* d_ws, size_t ws_size,
                              hipStream_t stream) {
    const float* x  = (const float*)d_in[0];
    const float* u0 = (const float*)d_in[1];
    const float* v0 = (const float*)d_in[2];
    const float* w  = (const float*)d_in[3];
    const float* bl = (const float*)d_in[4];
    float* out = (float*)d_out;
    float* p0  = (float*)d_ws;

    const size_t need = (size_t)8 * 32 * 128 * 128 * sizeof(float);
    const int use_ws = (ws_size >= need) ? 1 : 0;

    if (use_ws) {
        einsum_kernel<<<512, 256, 0, stream>>>(x, w, bl, p0);
    }
    sim_kernel<<<256, 512, 0, stream>>>(u0, v0, p0, x, w, bl, out, use_ws);
}